// Round 1
// baseline (169.588 us; speedup 1.0000x reference)
//
#include <hip/hip_runtime.h>

#define HID 32

// tanh(x) = 1 - 2/(exp(2x)+1); v_exp_f32 + v_rcp_f32, no branches.
// x->+inf: e=inf, rcp(inf)=0 -> 1. x->-inf: e=0, rcp(1)=1 -> -1. Correct limits.
__device__ __forceinline__ float fast_tanh(float x) {
    float e = __expf(2.0f * x);
    float r = __builtin_amdgcn_rcpf(e + 1.0f);
    return __builtin_fmaf(-2.0f, r, 1.0f);
}

__global__ __launch_bounds__(256) void damping_kernel(
    const float* __restrict__ x,
    const float* __restrict__ w_d1, const float* __restrict__ w_d2, const float* __restrict__ w_d3,
    const float* __restrict__ w_o1, const float* __restrict__ w_o2, const float* __restrict__ w_o3,
    const float* __restrict__ b_d1, const float* __restrict__ b_d2, const float* __restrict__ b_d3,
    const float* __restrict__ b_o1, const float* __restrict__ b_o2, const float* __restrict__ b_o3,
    float* __restrict__ out, int n)
{
    int row = blockIdx.x * blockDim.x + threadIdx.x;
    if (row >= n) return;

    float2 xv = ((const float2*)x)[row];
    float x0 = xv.x, x1 = xv.y;

    float h[HID];
    float acc[HID];

    // ---------------- d branch ----------------
    // layer 1: 2 -> 32, tanh
    #pragma unroll
    for (int j = 0; j < HID; ++j)
        h[j] = fast_tanh(fmaf(x1, w_d1[HID + j], fmaf(x0, w_d1[j], b_d1[j])));

    // layer 2: 32 -> 32, tanh. k-outer so weight loads are contiguous (s_load_dwordx16 friendly)
    #pragma unroll
    for (int j = 0; j < HID; ++j) acc[j] = b_d2[j];
    #pragma unroll
    for (int k = 0; k < HID; ++k) {
        float hk = h[k];
        #pragma unroll
        for (int j = 0; j < HID; ++j) acc[j] = fmaf(hk, w_d2[k * HID + j], acc[j]);
    }
    #pragma unroll
    for (int j = 0; j < HID; ++j) h[j] = fast_tanh(acc[j]);

    // layer 3: 32 -> 2
    float d30 = b_d3[0], d31 = b_d3[1];
    #pragma unroll
    for (int k = 0; k < HID; ++k) {
        d30 = fmaf(h[k], w_d3[2 * k + 0], d30);
        d31 = fmaf(h[k], w_d3[2 * k + 1], d31);
    }
    float a = (fmaxf(d30, 0.0f) + 0.001f) * x0;
    float b = (fmaxf(d31, 0.0f) + 0.001f) * x1;

    // ---------------- o branch ----------------
    #pragma unroll
    for (int j = 0; j < HID; ++j)
        h[j] = fast_tanh(fmaf(x1, w_o1[HID + j], fmaf(x0, w_o1[j], b_o1[j])));

    #pragma unroll
    for (int j = 0; j < HID; ++j) acc[j] = b_o2[j];
    #pragma unroll
    for (int k = 0; k < HID; ++k) {
        float hk = h[k];
        #pragma unroll
        for (int j = 0; j < HID; ++j) acc[j] = fmaf(hk, w_o2[k * HID + j], acc[j]);
    }
    #pragma unroll
    for (int j = 0; j < HID; ++j) h[j] = fast_tanh(acc[j]);

    float o3 = b_o3[0];
    #pragma unroll
    for (int k = 0; k < HID; ++k) o3 = fmaf(h[k], w_o3[k], o3);
    float c = o3;

    // ---------------- epilogue ----------------
    float D0 = fmaf(a * a, x0, a * c * x1);
    float D1 = fmaf(a * c, x0, fmaf(c, c, b * b) * x1);

    ((float2*)out)[row] = make_float2(D0, D1);
}

extern "C" void kernel_launch(void* const* d_in, const int* in_sizes, int n_in,
                              void* d_out, int out_size, void* d_ws, size_t ws_size,
                              hipStream_t stream) {
    const float* x    = (const float*)d_in[0];
    const float* w_d1 = (const float*)d_in[1];
    const float* w_d2 = (const float*)d_in[2];
    const float* w_d3 = (const float*)d_in[3];
    const float* w_o1 = (const float*)d_in[4];
    const float* w_o2 = (const float*)d_in[5];
    const float* w_o3 = (const float*)d_in[6];
    const float* b_d1 = (const float*)d_in[7];
    const float* b_d2 = (const float*)d_in[8];
    const float* b_d3 = (const float*)d_in[9];
    const float* b_o1 = (const float*)d_in[10];
    const float* b_o2 = (const float*)d_in[11];
    const float* b_o3 = (const float*)d_in[12];
    float* out = (float*)d_out;

    int n = in_sizes[0] / 2;  // number of rows
    int block = 256;
    int grid = (n + block - 1) / block;
    damping_kernel<<<grid, block, 0, stream>>>(
        x, w_d1, w_d2, w_d3, w_o1, w_o2, w_o3,
        b_d1, b_d2, b_d3, b_o1, b_o2, b_o3, out, n);
}

// Round 2
// 127.414 us; speedup vs baseline: 1.3310x; 1.3310x over previous
//
#include <hip/hip_runtime.h>

// Batch-as-N MFMA mapping: Y^T[j,b] = W^T[j,k] @ H^T[k,b] via mfma_f32_16x16x32_bf16.
// b (batch row within 16-tile) lives in lane&15 for the ENTIRE network:
//   B-frag (activations): lane holds n=lane&15, k = quad*8 + 0..7   (quad = lane>>4)
//   D      (outputs):     lane holds n=lane&15, j = t*16 + quad*4 + reg
// Layer1 (2->32) computes its 8 outputs directly in B-frag layout (no shuffle).
// Layer3 (32->{2,1}) is per-lane partials over the lane's 8 j-values + butterfly
// reduce over xor16/xor32 (the 4 quads partition j for fixed b).

typedef __bf16 bf16x8 __attribute__((ext_vector_type(8)));
typedef float f32x4 __attribute__((ext_vector_type(4)));
typedef int i32x4 __attribute__((ext_vector_type(4)));

__device__ __forceinline__ float fast_tanh(float x) {
    // tanh(x) = 1 - 2/(exp2(x*2*log2e)+1); correct saturation at +-inf.
    float e = __builtin_amdgcn_exp2f(x * 2.8853900817779268f);
    float r = __builtin_amdgcn_rcpf(e + 1.0f);
    return __builtin_fmaf(-2.0f, r, 1.0f);
}

// Pack two f32 -> bf16 pair (round-to-nearest via +0x8000, then take high halves).
__device__ __forceinline__ int pack_bf16(float f0, float f1) {
    unsigned u0 = __builtin_bit_cast(unsigned, f0) + 0x8000u;
    unsigned u1 = __builtin_bit_cast(unsigned, f1) + 0x8000u;
    return (int)__builtin_amdgcn_perm(u1, u0, 0x07060302u); // {u1.hi16, u0.hi16}
}

__global__ __launch_bounds__(256, 3) void damping_mfma(
    const float* __restrict__ x,
    const float* __restrict__ w_d1, const float* __restrict__ w_d2, const float* __restrict__ w_d3,
    const float* __restrict__ w_o1, const float* __restrict__ w_o2, const float* __restrict__ w_o3,
    const float* __restrict__ b_d1, const float* __restrict__ b_d2, const float* __restrict__ b_d3,
    const float* __restrict__ b_o1, const float* __restrict__ b_o2, const float* __restrict__ b_o3,
    float* __restrict__ out, int n_tiles)
{
    const int lane = threadIdx.x & 63;
    const int quad = lane >> 4;
    const int b16  = lane & 15;
    const int wid     = (int)((blockIdx.x * blockDim.x + threadIdx.x) >> 6);
    const int n_waves = (int)((gridDim.x * blockDim.x) >> 6);

    // ---------------- per-lane constant preload (once per wave) ----------------
    // Layer1 weights in B-frag k-order: k = quad*8 + j
    float w1d0[8], w1d1[8], bd1[8], w1o0[8], w1o1[8], bo1[8];
    #pragma unroll
    for (int j = 0; j < 8; ++j) {
        int k = quad * 8 + j;
        w1d0[j] = w_d1[k]; w1d1[j] = w_d1[32 + k]; bd1[j] = b_d1[k];
        w1o0[j] = w_o1[k]; w1o1[j] = w_o1[32 + k]; bo1[j] = b_o1[k];
    }
    // Layer2 A-frags: A[m][k] = W^T[j=t*16+m][k] = w[k*32 + t*16 + m]; m=b16, k=quad*8+j
    bf16x8 a_d2[2], a_o2[2];
    #pragma unroll
    for (int t = 0; t < 2; ++t) {
        #pragma unroll
        for (int j = 0; j < 8; ++j) {
            int k = quad * 8 + j;
            a_d2[t][j] = (__bf16)w_d2[k * 32 + t * 16 + b16];
            a_o2[t][j] = (__bf16)w_o2[k * 32 + t * 16 + b16];
        }
    }
    // Layer2 bias + layer3 weights at this lane's 8 j-values: j = (i>>2)*16 + quad*4 + (i&3)
    float bd2[8], bo2[8], w3d0[8], w3d1[8], w3o[8];
    #pragma unroll
    for (int i = 0; i < 8; ++i) {
        int jj = (i >> 2) * 16 + quad * 4 + (i & 3);
        bd2[i]  = b_d2[jj]; bo2[i] = b_o2[jj];
        w3d0[i] = w_d3[jj * 2]; w3d1[i] = w_d3[jj * 2 + 1];
        w3o[i]  = w_o3[jj];
    }
    const float bd3_0 = b_d3[0], bd3_1 = b_d3[1], bo3_0 = b_o3[0];

    const float2* x2 = (const float2*)x;
    int tile = wid;
    if (tile >= n_tiles) return;
    float2 xv = x2[tile * 16 + b16];

    for (; tile < n_tiles; tile += n_waves) {
        // software prefetch next tile's x (clamped; hides VMEM latency behind compute)
        int nt = tile + n_waves;
        nt = (nt < n_tiles) ? nt : tile;
        float2 xnext = x2[nt * 16 + b16];

        const float x0 = xv.x, x1 = xv.y;

        // -------- layer 1 (both branches), directly in B-frag layout --------
        float hd[8], ho[8];
        #pragma unroll
        for (int j = 0; j < 8; ++j) {
            hd[j] = fast_tanh(fmaf(x1, w1d1[j], fmaf(x0, w1d0[j], bd1[j])));
            ho[j] = fast_tanh(fmaf(x1, w1o1[j], fmaf(x0, w1o0[j], bo1[j])));
        }
        i32x4 pd_, po_;
        #pragma unroll
        for (int p = 0; p < 4; ++p) {
            pd_[p] = pack_bf16(hd[2 * p], hd[2 * p + 1]);
            po_[p] = pack_bf16(ho[2 * p], ho[2 * p + 1]);
        }
        bf16x8 bfd = __builtin_bit_cast(bf16x8, pd_);
        bf16x8 bfo = __builtin_bit_cast(bf16x8, po_);

        // -------- layer 2: 4 independent MFMAs (2 j-tiles x 2 branches) --------
        f32x4 zero = {0.f, 0.f, 0.f, 0.f};
        f32x4 d0 = __builtin_amdgcn_mfma_f32_16x16x32_bf16(a_d2[0], bfd, zero, 0, 0, 0);
        f32x4 d1 = __builtin_amdgcn_mfma_f32_16x16x32_bf16(a_d2[1], bfd, zero, 0, 0, 0);
        f32x4 o0 = __builtin_amdgcn_mfma_f32_16x16x32_bf16(a_o2[0], bfo, zero, 0, 0, 0);
        f32x4 o1 = __builtin_amdgcn_mfma_f32_16x16x32_bf16(a_o2[1], bfo, zero, 0, 0, 0);

        // -------- layer 2 act + layer 3 partials --------
        float pd0 = 0.f, pd1 = 0.f, po = 0.f;
        #pragma unroll
        for (int i = 0; i < 8; ++i) {
            float vd = (i < 4 ? d0[i] : d1[i - 4]) + bd2[i];
            float vo = (i < 4 ? o0[i] : o1[i - 4]) + bo2[i];
            float h2d = fast_tanh(vd);
            float h2o = fast_tanh(vo);
            pd0 = fmaf(h2d, w3d0[i], pd0);
            pd1 = fmaf(h2d, w3d1[i], pd1);
            po  = fmaf(h2o, w3o[i], po);
        }
        // butterfly reduce across the 4 quads (same b16)
        pd0 += __shfl_xor(pd0, 16); pd0 += __shfl_xor(pd0, 32);
        pd1 += __shfl_xor(pd1, 16); pd1 += __shfl_xor(pd1, 32);
        po  += __shfl_xor(po, 16);  po  += __shfl_xor(po, 32);

        // -------- epilogue --------
        float d30 = pd0 + bd3_0, d31 = pd1 + bd3_1, c = po + bo3_0;
        float a = (fmaxf(d30, 0.f) + 0.001f) * x0;
        float b = (fmaxf(d31, 0.f) + 0.001f) * x1;
        float D0 = fmaf(a * a, x0, a * c * x1);
        float D1 = fmaf(a * c, x0, fmaf(c, c, b * b) * x1);

        if (quad == 0) ((float2*)out)[tile * 16 + b16] = make_float2(D0, D1);
        xv = xnext;
    }
}

extern "C" void kernel_launch(void* const* d_in, const int* in_sizes, int n_in,
                              void* d_out, int out_size, void* d_ws, size_t ws_size,
                              hipStream_t stream) {
    const float* x    = (const float*)d_in[0];
    const float* w_d1 = (const float*)d_in[1];
    const float* w_d2 = (const float*)d_in[2];
    const float* w_d3 = (const float*)d_in[3];
    const float* w_o1 = (const float*)d_in[4];
    const float* w_o2 = (const float*)d_in[5];
    const float* w_o3 = (const float*)d_in[6];
    const float* b_d1 = (const float*)d_in[7];
    const float* b_d2 = (const float*)d_in[8];
    const float* b_d3 = (const float*)d_in[9];
    const float* b_o1 = (const float*)d_in[10];
    const float* b_o2 = (const float*)d_in[11];
    const float* b_o3 = (const float*)d_in[12];
    float* out = (float*)d_out;

    int n = in_sizes[0] / 2;         // rows
    int n_tiles = n / 16;            // 16 rows per wave-iteration
    // 768 blocks * 4 waves = 3072 waves = 3 waves/SIMD at 1024 SIMDs (matches launch_bounds)
    int blocks_needed = (n_tiles + 3) / 4;
    int grid = blocks_needed < 768 ? blocks_needed : 768;
    damping_mfma<<<grid, 256, 0, stream>>>(
        x, w_d1, w_d2, w_d3, w_o1, w_o2, w_o3,
        b_d1, b_d2, b_d3, b_o1, b_o2, b_o3, out, n_tiles);
}